// Round 6
// baseline (288.067 us; speedup 1.0000x reference)
//
#include <hip/hip_runtime.h>

// Shapes: G=8 S=140 D=256 K=12 NEG=128 W=128 POOL=20000
#define NG 8
#define NS 140
#define ND 256
#define NK 12
#define NNEG 128
#define NW 128
#define POOLN 20000

typedef __attribute__((ext_vector_type(8))) short short8;
typedef __attribute__((ext_vector_type(4))) float f32x4;
typedef __attribute__((ext_vector_type(4))) unsigned int u32x4;

__device__ inline unsigned short f2bf(float f) {
    union { float f; unsigned u; } v; v.f = f;
    unsigned r = v.u + 0x7FFFu + ((v.u >> 16) & 1u);   // RNE
    return (unsigned short)(r >> 16);
}
__device__ inline float bf2f(unsigned short u) {
    union { unsigned u; float f; } v; v.u = ((unsigned)u) << 16;
    return v.f;
}
__device__ inline uint4 pack8(const float* p) {
    float4 x = *(const float4*)p, y = *(const float4*)(p + 4);
    uint4 u;
    u.x = f2bf(x.x) | ((unsigned)f2bf(x.y) << 16);
    u.y = f2bf(x.z) | ((unsigned)f2bf(x.w) << 16);
    u.z = f2bf(y.x) | ((unsigned)f2bf(y.y) << 16);
    u.w = f2bf(y.z) | ((unsigned)f2bf(y.w) << 16);
    return u;
}

#define P1PAD 72
#define CVT_N8 (POOLN * ND / 8)               // 640000 groups of 8
#define CVT_BLOCKS ((CVT_N8 + 255) / 256)     // 2500
#define LOC_BLOCKS 768                        // 16 x 48
#define TR_BLOCKS 512                         // extIdx transpose: 131072 elems

// ---------- fused prep: pool cvt + locC GEMM + extIdx transpose + counter zero ----------
__global__ __launch_bounds__(256) void k_prep(const float* __restrict__ cF,
                                              const float* __restrict__ Wm,
                                              const float* __restrict__ other,
                                              const int* __restrict__ extIdx,
                                              unsigned short* __restrict__ pool_bf,
                                              unsigned short* __restrict__ locC_bf,
                                              int* __restrict__ extIdxT,
                                              int* __restrict__ doneCnt) {
    int bid = blockIdx.x;
    int tid = threadIdx.x;
    if (bid == 0 && tid == 0) *doneCnt = 0;
    if (bid >= LOC_BLOCKS + CVT_BLOCKS) {
        // extIdxT[(g*128+w)*128+n] = extIdx[(g*128+n)*128+w]
        int t = (bid - LOC_BLOCKS - CVT_BLOCKS) * 256 + tid;   // 0..131071
        int gw = t >> 7, n = t & 127;
        int g = gw >> 7, w = gw & 127;
        extIdxT[t] = extIdx[(g * NNEG + n) * NW + w];
        return;
    }
    if (bid >= LOC_BLOCKS) {
        int t = (bid - LOC_BLOCKS) * 256 + tid;
        if (t < CVT_N8) {
            uint4 u = pack8(other + t * 8);
            *(uint4*)(pool_bf + t * 8) = u;
        }
        return;
    }
    // -------- locC GEMM branch --------
    __shared__ unsigned short As[64 * P1PAD];
    __shared__ unsigned short Bs[64 * P1PAD];
    int m0 = (bid & 15) * 64, n0 = (bid >> 4) * 64;
    int lane = tid & 63, wv = tid >> 6;
    int wm = (wv >> 1) * 32, wn = (wv & 1) * 32;
    int lm = lane & 15, quad = lane >> 4;
    int r = tid >> 2, q = tid & 3;
    int g = (m0 + r) >> 7, w = (m0 + r) & 127;
    const float* aSrc = cF + (g * NS + w) * ND + q * 16;
    const float* bSrc = Wm + (n0 + r) * ND + q * 16;
    f32x4 acc[2][2] = {};
    for (int kt = 0; kt < 256; kt += 64) {
        uint4 a0 = pack8(aSrc + kt);
        uint4 a1 = pack8(aSrc + kt + 8);
        uint4 b0 = pack8(bSrc + kt);
        uint4 b1 = pack8(bSrc + kt + 8);
        if (kt) __syncthreads();
        *(uint4*)&As[r * P1PAD + q * 16] = a0;
        *(uint4*)&As[r * P1PAD + q * 16 + 8] = a1;
        *(uint4*)&Bs[r * P1PAD + q * 16] = b0;
        *(uint4*)&Bs[r * P1PAD + q * 16 + 8] = b1;
        __syncthreads();
        #pragma unroll
        for (int ks = 0; ks < 2; ++ks) {
            short8 af[2], bf[2];
            #pragma unroll
            for (int mt = 0; mt < 2; ++mt)
                af[mt] = *(const short8*)&As[(wm + mt * 16 + lm) * P1PAD + ks * 32 + quad * 8];
            #pragma unroll
            for (int nt = 0; nt < 2; ++nt)
                bf[nt] = *(const short8*)&Bs[(wn + nt * 16 + lm) * P1PAD + ks * 32 + quad * 8];
            #pragma unroll
            for (int mt = 0; mt < 2; ++mt)
                #pragma unroll
                for (int nt = 0; nt < 2; ++nt)
                    acc[mt][nt] = __builtin_amdgcn_mfma_f32_16x16x32_bf16(
                        af[mt], bf[nt], acc[mt][nt], 0, 0, 0);
        }
    }
    #pragma unroll
    for (int mt = 0; mt < 2; ++mt)
        #pragma unroll
        for (int nt = 0; nt < 2; ++nt)
            #pragma unroll
            for (int rr = 0; rr < 4; ++rr) {
                int row = m0 + wm + mt * 16 + quad * 4 + rr;
                int col = n0 + wn + nt * 16 + lm;
                locC_bf[(long)row * 3072 + col] = f2bf(acc[mt][nt][rr]);
            }
}

// ---------- scores: register gather (loads pinned in flight) + MFMA + softmax ----------
// 512 threads (8 waves); wave wv owns 16 neg rows; lane (lm,quad) loads 8x16B
// fragments of row n=wv*16+lm. asm pin forces all 8 loads issued before the
// locC staging barrier -> one vmcnt drain, not 8 serialized waits.
__global__ __launch_bounds__(512) void k_scores(const unsigned short* __restrict__ locC,
                                                const float* __restrict__ gtP,
                                                const unsigned short* __restrict__ pool,
                                                const int* __restrict__ extIdxT,
                                                float* __restrict__ partial,
                                                int* __restrict__ doneCnt,
                                                float* __restrict__ out) {
    __shared__ unsigned short locS[16 * 264];
    __shared__ float sc[NK][132];
    __shared__ float spos[NK];
    __shared__ int isLast;

    int bid = blockIdx.x;
    int g = bid >> 7, w = bid & 127;
    int tid = threadIdx.x, lane = tid & 63, wv = tid >> 6;
    int lm = lane & 15, quad = lane >> 4;

    // gather: coalesced index load, then ALL 8 fragment loads, pinned
    int n = wv * 16 + lm;
    long rowIdx = (long)extIdxT[bid * NNEG + n];
    const u32x4* pb = (const u32x4*)(pool + rowIdx * 256) + quad;
    u32x4 q0 = pb[0],  q1 = pb[4],  q2 = pb[8],  q3 = pb[12];
    u32x4 q4 = pb[16], q5 = pb[20], q6 = pb[24], q7 = pb[28];
    asm volatile("" : "+v"(q0), "+v"(q1), "+v"(q2), "+v"(q3),
                      "+v"(q4), "+v"(q5), "+v"(q6), "+v"(q7));

    // stage locC 12x256 (+4 zero rows) while gathers are in flight
    const uint4* src = (const uint4*)(locC + (long)bid * 3072);
    if (tid < 384) {
        int k = tid >> 5, e8 = tid & 31;
        *(uint4*)&locS[k * 264 + e8 * 8] = src[tid];
    } else {
        int f = tid - 384;
        int k = 12 + (f >> 5), e8 = f & 31;
        *(uint4*)&locS[k * 264 + e8 * 8] = make_uint4(0, 0, 0, 0);
    }
    __syncthreads();

    // positive scores: waves 0..5, 2 k's each
    if (wv < 6) {
        #pragma unroll
        for (int c = 0; c < 2; ++c) {
            int k = wv * 2 + c;
            float4 gv = *(const float4*)(gtP + (g * NS + w + 1 + k) * ND + lane * 4);
            const unsigned short* lp = &locS[k * 264 + lane * 4];
            float s = bf2f(lp[0]) * gv.x + bf2f(lp[1]) * gv.y +
                      bf2f(lp[2]) * gv.z + bf2f(lp[3]) * gv.w;
            for (int off = 32; off; off >>= 1) s += __shfl_xor(s, off);
            if (!lane) spos[k] = s * (1.0f / 256.0f);
        }
    }

    // neg scores: 8 MFMAs, two independent accumulator chains
    const short8* aP = (const short8*)&locS[lm * 264 + quad * 8];
    f32x4 accA = {0.f, 0.f, 0.f, 0.f}, accB = {0.f, 0.f, 0.f, 0.f};
    accA = __builtin_amdgcn_mfma_f32_16x16x32_bf16(aP[0],  __builtin_bit_cast(short8, q0), accA, 0, 0, 0);
    accB = __builtin_amdgcn_mfma_f32_16x16x32_bf16(aP[4],  __builtin_bit_cast(short8, q1), accB, 0, 0, 0);
    accA = __builtin_amdgcn_mfma_f32_16x16x32_bf16(aP[8],  __builtin_bit_cast(short8, q2), accA, 0, 0, 0);
    accB = __builtin_amdgcn_mfma_f32_16x16x32_bf16(aP[12], __builtin_bit_cast(short8, q3), accB, 0, 0, 0);
    accA = __builtin_amdgcn_mfma_f32_16x16x32_bf16(aP[16], __builtin_bit_cast(short8, q4), accA, 0, 0, 0);
    accB = __builtin_amdgcn_mfma_f32_16x16x32_bf16(aP[20], __builtin_bit_cast(short8, q5), accB, 0, 0, 0);
    accA = __builtin_amdgcn_mfma_f32_16x16x32_bf16(aP[24], __builtin_bit_cast(short8, q6), accA, 0, 0, 0);
    accB = __builtin_amdgcn_mfma_f32_16x16x32_bf16(aP[28], __builtin_bit_cast(short8, q7), accB, 0, 0, 0);
    #pragma unroll
    for (int rr = 0; rr < 4; ++rr) {
        int k = quad * 4 + rr;
        if (k < NK) sc[k][n] = (accA[rr] + accB[rr]) * (1.0f / 256.0f);
    }
    __syncthreads();

    // per-k log-softmax over [pos, 128 negs]; 16-thread teams per k
    if (tid < NK * 16) {
        int k = tid >> 4, i = tid & 15;
        float vals[8];
        float mx = -1e30f;
        for (int j = 0; j < 8; ++j) {
            vals[j] = sc[k][i + 16 * j];
            mx = fmaxf(mx, vals[j]);
        }
        for (int off = 8; off > 0; off >>= 1) mx = fmaxf(mx, __shfl_xor(mx, off, 16));
        float negmax = mx;
        float sp = spos[k];
        float M = fmaxf(negmax, sp);
        float se = 0.f;
        for (int j = 0; j < 8; ++j) se += __expf(vals[j] - M);
        for (int off = 8; off > 0; off >>= 1) se += __shfl_xor(se, off, 16);
        if (i == 0) {
            float total = se + __expf(sp - M);
            float lp = sp - (M + __logf(total));
            partial[k * 1024 + bid]        = -lp;
            partial[(NK + k) * 1024 + bid] = (sp >= negmax) ? 1.0f : 0.0f;
        }
    }

    // ---- last block reduces the partials (no extra launch) ----
    __threadfence();                          // release partials (device scope)
    if (tid == 0) isLast = (atomicAdd(doneCnt, 1) == 1023);
    __syncthreads();
    if (isLast) {
        __threadfence();                      // acquire
        for (int j = wv; j < 24; j += 8) {
            const float* p = partial + j * 1024;
            float s = 0.f;
            for (int t = lane; t < 1024; t += 64) s += p[t];
            for (int off = 32; off; off >>= 1) s += __shfl_xor(s, off);
            if (!lane) out[j] = s * (1.0f / 1024.0f);
        }
    }
}

extern "C" void kernel_launch(void* const* d_in, const int* in_sizes, int n_in,
                              void* d_out, int out_size, void* d_ws, size_t ws_size,
                              hipStream_t stream) {
    const float* cF     = (const float*)d_in[0];   // (8,140,256)
    const float* gtP    = (const float*)d_in[1];   // (8,140,256)
    const float* other  = (const float*)d_in[2];   // (20000,256)
    const int*   extIdx = (const int*)  d_in[3];   // (8,128,128)
    const float* Wm     = (const float*)d_in[4];   // (12,256,256)
    float* out = (float*)d_out;                    // 12 losses then 12 acc

    unsigned short* pool_bf = (unsigned short*)d_ws;       // 20000*256 shorts = 10.24 MB
    unsigned short* locC_bf = pool_bf + (long)POOLN * ND;  // 1024*3072 shorts = 6.29 MB
    int* extIdxT = (int*)(locC_bf + (long)1024 * 3072);    // 131072 ints = 512 KB
    float* partial = (float*)(extIdxT + 131072);           // 24*1024 floats = 96 KB
    int* doneCnt = (int*)(partial + 24 * 1024);            // 1 int

    k_prep<<<LOC_BLOCKS + CVT_BLOCKS + TR_BLOCKS, 256, 0, stream>>>(
        cF, Wm, other, extIdx, pool_bf, locC_bf, extIdxT, doneCnt);
    k_scores<<<1024, 512, 0, stream>>>(locC_bf, gtP, pool_bf, extIdxT,
                                       partial, doneCnt, out);
}

// Round 7
// 98.650 us; speedup vs baseline: 2.9201x; 2.9201x over previous
//
#include <hip/hip_runtime.h>

// Shapes: G=8 S=140 D=256 K=12 NEG=128 W=128 POOL=20000
#define NG 8
#define NS 140
#define ND 256
#define NK 12
#define NNEG 128
#define NW 128
#define POOLN 20000

typedef __attribute__((ext_vector_type(8))) short short8;
typedef __attribute__((ext_vector_type(4))) float f32x4;
typedef __attribute__((ext_vector_type(4))) unsigned int u32x4;

__device__ inline unsigned short f2bf(float f) {
    union { float f; unsigned u; } v; v.f = f;
    unsigned r = v.u + 0x7FFFu + ((v.u >> 16) & 1u);   // RNE
    return (unsigned short)(r >> 16);
}
__device__ inline float bf2f(unsigned short u) {
    union { unsigned u; float f; } v; v.u = ((unsigned)u) << 16;
    return v.f;
}
__device__ inline uint4 pack8(const float* p) {
    float4 x = *(const float4*)p, y = *(const float4*)(p + 4);
    uint4 u;
    u.x = f2bf(x.x) | ((unsigned)f2bf(x.y) << 16);
    u.y = f2bf(x.z) | ((unsigned)f2bf(x.w) << 16);
    u.z = f2bf(y.x) | ((unsigned)f2bf(y.y) << 16);
    u.w = f2bf(y.z) | ((unsigned)f2bf(y.w) << 16);
    return u;
}

#define P1PAD 72
#define CVT_N8 (POOLN * ND / 8)               // 640000 groups of 8
#define CVT_BLOCKS ((CVT_N8 + 255) / 256)     // 2500
#define LOC_BLOCKS 768                        // 16 x 48
#define TR_BLOCKS 512                         // extIdx transpose: 131072 elems

// ---------- fused prep: pool cvt + locC GEMM + extIdx transpose ----------
__global__ __launch_bounds__(256) void k_prep(const float* __restrict__ cF,
                                              const float* __restrict__ Wm,
                                              const float* __restrict__ other,
                                              const int* __restrict__ extIdx,
                                              unsigned short* __restrict__ pool_bf,
                                              unsigned short* __restrict__ locC_bf,
                                              int* __restrict__ extIdxT) {
    int bid = blockIdx.x;
    int tid = threadIdx.x;
    if (bid >= LOC_BLOCKS + CVT_BLOCKS) {
        // extIdxT[(g*128+w)*128+n] = extIdx[(g*128+n)*128+w]
        int t = (bid - LOC_BLOCKS - CVT_BLOCKS) * 256 + tid;   // 0..131071
        int gw = t >> 7, n = t & 127;
        int g = gw >> 7, w = gw & 127;
        extIdxT[t] = extIdx[(g * NNEG + n) * NW + w];
        return;
    }
    if (bid >= LOC_BLOCKS) {
        int t = (bid - LOC_BLOCKS) * 256 + tid;
        if (t < CVT_N8) {
            uint4 u = pack8(other + t * 8);
            *(uint4*)(pool_bf + t * 8) = u;
        }
        return;
    }
    // -------- locC GEMM branch --------
    __shared__ unsigned short As[64 * P1PAD];
    __shared__ unsigned short Bs[64 * P1PAD];
    int m0 = (bid & 15) * 64, n0 = (bid >> 4) * 64;
    int lane = tid & 63, wv = tid >> 6;
    int wm = (wv >> 1) * 32, wn = (wv & 1) * 32;
    int lm = lane & 15, quad = lane >> 4;
    int r = tid >> 2, q = tid & 3;
    int g = (m0 + r) >> 7, w = (m0 + r) & 127;
    const float* aSrc = cF + (g * NS + w) * ND + q * 16;
    const float* bSrc = Wm + (n0 + r) * ND + q * 16;
    f32x4 acc[2][2] = {};
    for (int kt = 0; kt < 256; kt += 64) {
        uint4 a0 = pack8(aSrc + kt);
        uint4 a1 = pack8(aSrc + kt + 8);
        uint4 b0 = pack8(bSrc + kt);
        uint4 b1 = pack8(bSrc + kt + 8);
        if (kt) __syncthreads();
        *(uint4*)&As[r * P1PAD + q * 16] = a0;
        *(uint4*)&As[r * P1PAD + q * 16 + 8] = a1;
        *(uint4*)&Bs[r * P1PAD + q * 16] = b0;
        *(uint4*)&Bs[r * P1PAD + q * 16 + 8] = b1;
        __syncthreads();
        #pragma unroll
        for (int ks = 0; ks < 2; ++ks) {
            short8 af[2], bf[2];
            #pragma unroll
            for (int mt = 0; mt < 2; ++mt)
                af[mt] = *(const short8*)&As[(wm + mt * 16 + lm) * P1PAD + ks * 32 + quad * 8];
            #pragma unroll
            for (int nt = 0; nt < 2; ++nt)
                bf[nt] = *(const short8*)&Bs[(wn + nt * 16 + lm) * P1PAD + ks * 32 + quad * 8];
            #pragma unroll
            for (int mt = 0; mt < 2; ++mt)
                #pragma unroll
                for (int nt = 0; nt < 2; ++nt)
                    acc[mt][nt] = __builtin_amdgcn_mfma_f32_16x16x32_bf16(
                        af[mt], bf[nt], acc[mt][nt], 0, 0, 0);
        }
    }
    #pragma unroll
    for (int mt = 0; mt < 2; ++mt)
        #pragma unroll
        for (int nt = 0; nt < 2; ++nt)
            #pragma unroll
            for (int rr = 0; rr < 4; ++rr) {
                int row = m0 + wm + mt * 16 + quad * 4 + rr;
                int col = n0 + wn + nt * 16 + lm;
                locC_bf[(long)row * 3072 + col] = f2bf(acc[mt][nt][rr]);
            }
}

// ---------- scores: register gather, loads force-pinned before barrier ----------
// 512 threads (8 waves); wave wv owns 16 neg rows; lane (lm,quad) loads 8x16B
// fragments of row n=wv*16+lm. The memory-clobber pin after the LDS staging
// stores prevents the compiler from sinking the gathers to their uses: all 8
// issue back-to-back, one vmcnt drain at the barrier. NO device-scope fences
// (R5/R6 lesson: per-block __threadfence => serialized L2 writebacks, +190us).
__global__ __launch_bounds__(512) void k_scores(const unsigned short* __restrict__ locC,
                                                const float* __restrict__ gtP,
                                                const unsigned short* __restrict__ pool,
                                                const int* __restrict__ extIdxT,
                                                float* __restrict__ partial) {
    __shared__ unsigned short locS[16 * 264];
    __shared__ float sc[NK][132];
    __shared__ float spos[NK];

    int bid = blockIdx.x;
    int g = bid >> 7, w = bid & 127;
    int tid = threadIdx.x, lane = tid & 63, wv = tid >> 6;
    int lm = lane & 15, quad = lane >> 4;

    // gather: coalesced index load, then ALL 8 fragment loads
    int n = wv * 16 + lm;
    long rowIdx = (long)extIdxT[bid * NNEG + n];
    const u32x4* pb = (const u32x4*)(pool + rowIdx * 256) + quad;
    u32x4 q0 = pb[0],  q1 = pb[4],  q2 = pb[8],  q3 = pb[12];
    u32x4 q4 = pb[16], q5 = pb[20], q6 = pb[24], q7 = pb[28];

    // stage locC 12x256 (+4 zero rows) while gathers are in flight
    const uint4* src = (const uint4*)(locC + (long)bid * 3072);
    if (tid < 384) {
        int k = tid >> 5, e8 = tid & 31;
        *(uint4*)&locS[k * 264 + e8 * 8] = src[tid];
    } else {
        int f = tid - 384;
        int k = 12 + (f >> 5), e8 = f & 31;
        *(uint4*)&locS[k * 264 + e8 * 8] = make_uint4(0, 0, 0, 0);
    }
    // pin: loads cannot sink past this (data dep); this cannot move above the
    // LDS stores (memory clobber) -> gathers are issued before the barrier.
    asm volatile("" : "+v"(q0), "+v"(q1), "+v"(q2), "+v"(q3),
                      "+v"(q4), "+v"(q5), "+v"(q6), "+v"(q7) :: "memory");
    __syncthreads();

    // positive scores: waves 0..5, 2 k's each
    if (wv < 6) {
        #pragma unroll
        for (int c = 0; c < 2; ++c) {
            int k = wv * 2 + c;
            float4 gv = *(const float4*)(gtP + (g * NS + w + 1 + k) * ND + lane * 4);
            const unsigned short* lp = &locS[k * 264 + lane * 4];
            float s = bf2f(lp[0]) * gv.x + bf2f(lp[1]) * gv.y +
                      bf2f(lp[2]) * gv.z + bf2f(lp[3]) * gv.w;
            for (int off = 32; off; off >>= 1) s += __shfl_xor(s, off);
            if (!lane) spos[k] = s * (1.0f / 256.0f);
        }
    }

    // neg scores: 8 MFMAs, two independent accumulator chains
    const short8* aP = (const short8*)&locS[lm * 264 + quad * 8];
    f32x4 accA = {0.f, 0.f, 0.f, 0.f}, accB = {0.f, 0.f, 0.f, 0.f};
    accA = __builtin_amdgcn_mfma_f32_16x16x32_bf16(aP[0],  __builtin_bit_cast(short8, q0), accA, 0, 0, 0);
    accB = __builtin_amdgcn_mfma_f32_16x16x32_bf16(aP[4],  __builtin_bit_cast(short8, q1), accB, 0, 0, 0);
    accA = __builtin_amdgcn_mfma_f32_16x16x32_bf16(aP[8],  __builtin_bit_cast(short8, q2), accA, 0, 0, 0);
    accB = __builtin_amdgcn_mfma_f32_16x16x32_bf16(aP[12], __builtin_bit_cast(short8, q3), accB, 0, 0, 0);
    accA = __builtin_amdgcn_mfma_f32_16x16x32_bf16(aP[16], __builtin_bit_cast(short8, q4), accA, 0, 0, 0);
    accB = __builtin_amdgcn_mfma_f32_16x16x32_bf16(aP[20], __builtin_bit_cast(short8, q5), accB, 0, 0, 0);
    accA = __builtin_amdgcn_mfma_f32_16x16x32_bf16(aP[24], __builtin_bit_cast(short8, q6), accA, 0, 0, 0);
    accB = __builtin_amdgcn_mfma_f32_16x16x32_bf16(aP[28], __builtin_bit_cast(short8, q7), accB, 0, 0, 0);
    #pragma unroll
    for (int rr = 0; rr < 4; ++rr) {
        int k = quad * 4 + rr;
        if (k < NK) sc[k][n] = (accA[rr] + accB[rr]) * (1.0f / 256.0f);
    }
    __syncthreads();

    // per-k log-softmax over [pos, 128 negs]; 16-thread teams per k
    if (tid < NK * 16) {
        int k = tid >> 4, i = tid & 15;
        float vals[8];
        float mx = -1e30f;
        for (int j = 0; j < 8; ++j) {
            vals[j] = sc[k][i + 16 * j];
            mx = fmaxf(mx, vals[j]);
        }
        for (int off = 8; off > 0; off >>= 1) mx = fmaxf(mx, __shfl_xor(mx, off, 16));
        float negmax = mx;
        float sp = spos[k];
        float M = fmaxf(negmax, sp);
        float se = 0.f;
        for (int j = 0; j < 8; ++j) se += __expf(vals[j] - M);
        for (int off = 8; off > 0; off >>= 1) se += __shfl_xor(se, off, 16);
        if (i == 0) {
            float total = se + __expf(sp - M);
            float lp = sp - (M + __logf(total));
            partial[k * 1024 + bid]        = -lp;
            partial[(NK + k) * 1024 + bid] = (sp >= negmax) ? 1.0f : 0.0f;
        }
    }
}

// ---------- final reduce: 24 outputs, sum 1024 partials each ----------
__global__ __launch_bounds__(256) void k_reduce(const float* __restrict__ partial,
                                                float* __restrict__ out) {
    int j = blockIdx.x;                 // 0..23
    int tid = threadIdx.x;
    const float* p = partial + j * 1024;
    float s = p[tid] + p[tid + 256] + p[tid + 512] + p[tid + 768];
    for (int off = 32; off; off >>= 1) s += __shfl_xor(s, off);
    __shared__ float wsum[4];
    if ((tid & 63) == 0) wsum[tid >> 6] = s;
    __syncthreads();
    if (tid == 0) out[j] = (wsum[0] + wsum[1] + wsum[2] + wsum[3]) * (1.0f / 1024.0f);
}

extern "C" void kernel_launch(void* const* d_in, const int* in_sizes, int n_in,
                              void* d_out, int out_size, void* d_ws, size_t ws_size,
                              hipStream_t stream) {
    const float* cF     = (const float*)d_in[0];   // (8,140,256)
    const float* gtP    = (const float*)d_in[1];   // (8,140,256)
    const float* other  = (const float*)d_in[2];   // (20000,256)
    const int*   extIdx = (const int*)  d_in[3];   // (8,128,128)
    const float* Wm     = (const float*)d_in[4];   // (12,256,256)
    float* out = (float*)d_out;                    // 12 losses then 12 acc

    unsigned short* pool_bf = (unsigned short*)d_ws;       // 20000*256 shorts = 10.24 MB
    unsigned short* locC_bf = pool_bf + (long)POOLN * ND;  // 1024*3072 shorts = 6.29 MB
    int* extIdxT = (int*)(locC_bf + (long)1024 * 3072);    // 131072 ints = 512 KB
    float* partial = (float*)(extIdxT + 131072);           // 24*1024 floats = 96 KB

    k_prep<<<LOC_BLOCKS + CVT_BLOCKS + TR_BLOCKS, 256, 0, stream>>>(
        cF, Wm, other, extIdx, pool_bf, locC_bf, extIdxT);
    k_scores<<<1024, 512, 0, stream>>>(locC_bf, gtP, pool_bf, extIdxT, partial);
    k_reduce<<<24, 256, 0, stream>>>(partial, out);
}

// Round 8
// 98.237 us; speedup vs baseline: 2.9324x; 1.0042x over previous
//
#include <hip/hip_runtime.h>

// Shapes: G=8 S=140 D=256 K=12 NEG=128 W=128 POOL=20000
#define NG 8
#define NS 140
#define ND 256
#define NK 12
#define NNEG 128
#define NW 128
#define POOLN 20000

typedef __attribute__((ext_vector_type(8))) short short8;
typedef __attribute__((ext_vector_type(4))) float f32x4;
typedef __attribute__((ext_vector_type(4))) unsigned int u32x4;

__device__ inline unsigned short f2bf(float f) {
    union { float f; unsigned u; } v; v.f = f;
    unsigned r = v.u + 0x7FFFu + ((v.u >> 16) & 1u);   // RNE
    return (unsigned short)(r >> 16);
}
__device__ inline float bf2f(unsigned short u) {
    union { unsigned u; float f; } v; v.u = ((unsigned)u) << 16;
    return v.f;
}
__device__ inline uint4 pack8(const float* p) {
    float4 x = *(const float4*)p, y = *(const float4*)(p + 4);
    uint4 u;
    u.x = f2bf(x.x) | ((unsigned)f2bf(x.y) << 16);
    u.y = f2bf(x.z) | ((unsigned)f2bf(x.w) << 16);
    u.z = f2bf(y.x) | ((unsigned)f2bf(y.y) << 16);
    u.w = f2bf(y.z) | ((unsigned)f2bf(y.w) << 16);
    return u;
}

#define P1PAD 72
#define CVT_N8 (POOLN * ND / 8)               // 640000 groups of 8
#define CVT_BLOCKS ((CVT_N8 + 255) / 256)     // 2500
#define GTP_N8 (NG * NS * ND / 8)             // 35840 groups of 8
#define GTP_BLOCKS (GTP_N8 / 256)             // 140
#define LOC_BLOCKS 768                        // 16 x 48
#define TR_BLOCKS 512                         // extIdx transpose: 131072 elems

// ---------- fused prep: pool cvt + gtP cvt + locC GEMM + extIdx transpose ----------
__global__ __launch_bounds__(256) void k_prep(const float* __restrict__ cF,
                                              const float* __restrict__ Wm,
                                              const float* __restrict__ other,
                                              const float* __restrict__ gtP,
                                              const int* __restrict__ extIdx,
                                              unsigned short* __restrict__ pool_bf,
                                              unsigned short* __restrict__ gtP_bf,
                                              unsigned short* __restrict__ locC_bf,
                                              int* __restrict__ extIdxT) {
    int bid = blockIdx.x;
    int tid = threadIdx.x;
    if (bid >= LOC_BLOCKS + CVT_BLOCKS + GTP_BLOCKS) {
        // extIdxT[(g*128+w)*128+n] = extIdx[(g*128+n)*128+w]
        int t = (bid - LOC_BLOCKS - CVT_BLOCKS - GTP_BLOCKS) * 256 + tid;  // 0..131071
        int gw = t >> 7, n = t & 127;
        int g = gw >> 7, w = gw & 127;
        extIdxT[t] = extIdx[(g * NNEG + n) * NW + w];
        return;
    }
    if (bid >= LOC_BLOCKS + CVT_BLOCKS) {
        // gtP fp32 -> bf16
        int t = (bid - LOC_BLOCKS - CVT_BLOCKS) * 256 + tid;
        uint4 u = pack8(gtP + t * 8);
        *(uint4*)(gtP_bf + t * 8) = u;
        return;
    }
    if (bid >= LOC_BLOCKS) {
        // pool fp32 -> bf16
        int t = (bid - LOC_BLOCKS) * 256 + tid;
        if (t < CVT_N8) {
            uint4 u = pack8(other + t * 8);
            *(uint4*)(pool_bf + t * 8) = u;
        }
        return;
    }
    // -------- locC GEMM branch --------
    __shared__ unsigned short As[64 * P1PAD];
    __shared__ unsigned short Bs[64 * P1PAD];
    int m0 = (bid & 15) * 64, n0 = (bid >> 4) * 64;
    int lane = tid & 63, wv = tid >> 6;
    int wm = (wv >> 1) * 32, wn = (wv & 1) * 32;
    int lm = lane & 15, quad = lane >> 4;
    int r = tid >> 2, q = tid & 3;
    int g = (m0 + r) >> 7, w = (m0 + r) & 127;
    const float* aSrc = cF + (g * NS + w) * ND + q * 16;
    const float* bSrc = Wm + (n0 + r) * ND + q * 16;
    f32x4 acc[2][2] = {};
    for (int kt = 0; kt < 256; kt += 64) {
        uint4 a0 = pack8(aSrc + kt);
        uint4 a1 = pack8(aSrc + kt + 8);
        uint4 b0 = pack8(bSrc + kt);
        uint4 b1 = pack8(bSrc + kt + 8);
        if (kt) __syncthreads();
        *(uint4*)&As[r * P1PAD + q * 16] = a0;
        *(uint4*)&As[r * P1PAD + q * 16 + 8] = a1;
        *(uint4*)&Bs[r * P1PAD + q * 16] = b0;
        *(uint4*)&Bs[r * P1PAD + q * 16 + 8] = b1;
        __syncthreads();
        #pragma unroll
        for (int ks = 0; ks < 2; ++ks) {
            short8 af[2], bf[2];
            #pragma unroll
            for (int mt = 0; mt < 2; ++mt)
                af[mt] = *(const short8*)&As[(wm + mt * 16 + lm) * P1PAD + ks * 32 + quad * 8];
            #pragma unroll
            for (int nt = 0; nt < 2; ++nt)
                bf[nt] = *(const short8*)&Bs[(wn + nt * 16 + lm) * P1PAD + ks * 32 + quad * 8];
            #pragma unroll
            for (int mt = 0; mt < 2; ++mt)
                #pragma unroll
                for (int nt = 0; nt < 2; ++nt)
                    acc[mt][nt] = __builtin_amdgcn_mfma_f32_16x16x32_bf16(
                        af[mt], bf[nt], acc[mt][nt], 0, 0, 0);
        }
    }
    #pragma unroll
    for (int mt = 0; mt < 2; ++mt)
        #pragma unroll
        for (int nt = 0; nt < 2; ++nt)
            #pragma unroll
            for (int rr = 0; rr < 4; ++rr) {
                int row = m0 + wm + mt * 16 + quad * 4 + rr;
                int col = n0 + wn + nt * 16 + lm;
                locC_bf[(long)row * 3072 + col] = f2bf(acc[mt][nt][rr]);
            }
}

// ---------- scores: register gather (pinned) + MFMA + softmax -> partials ----------
// 512 threads (8 waves); wave wv owns 16 neg rows; lane (lm,quad) loads 8x16B
// fragments of row n=wv*16+lm. Memory-clobber pin keeps all 8 gathers issued
// before the barrier (one vmcnt drain). NO device-scope fences (R5/R6 lesson:
// per-block __threadfence => serialized L2 writebacks, +190us).
__global__ __launch_bounds__(512) void k_scores(const unsigned short* __restrict__ locC,
                                                const unsigned short* __restrict__ gtPb,
                                                const unsigned short* __restrict__ pool,
                                                const int* __restrict__ extIdxT,
                                                float* __restrict__ partial) {
    __shared__ unsigned short locS[16 * 264];
    __shared__ float sc[NK][132];
    __shared__ float spos[NK];

    int bid = blockIdx.x;
    int g = bid >> 7, w = bid & 127;
    int tid = threadIdx.x, lane = tid & 63, wv = tid >> 6;
    int lm = lane & 15, quad = lane >> 4;

    // gather: coalesced index load, then ALL 8 fragment loads
    int n = wv * 16 + lm;
    long rowIdx = (long)extIdxT[bid * NNEG + n];
    const u32x4* pb = (const u32x4*)(pool + rowIdx * 256) + quad;
    u32x4 q0 = pb[0],  q1 = pb[4],  q2 = pb[8],  q3 = pb[12];
    u32x4 q4 = pb[16], q5 = pb[20], q6 = pb[24], q7 = pb[28];

    // stage locC 12x256 (+4 zero rows) while gathers are in flight
    const uint4* src = (const uint4*)(locC + (long)bid * 3072);
    if (tid < 384) {
        int k = tid >> 5, e8 = tid & 31;
        *(uint4*)&locS[k * 264 + e8 * 8] = src[tid];
    } else {
        int f = tid - 384;
        int k = 12 + (f >> 5), e8 = f & 31;
        *(uint4*)&locS[k * 264 + e8 * 8] = make_uint4(0, 0, 0, 0);
    }
    // pin: gathers can't sink past this (data dep); this can't move above the
    // LDS stores (memory clobber).
    asm volatile("" : "+v"(q0), "+v"(q1), "+v"(q2), "+v"(q3),
                      "+v"(q4), "+v"(q5), "+v"(q6), "+v"(q7) :: "memory");
    __syncthreads();

    // positive scores: waves 0..5, 2 k's each; bf16 gtP (8 B/lane)
    if (wv < 6) {
        #pragma unroll
        for (int c = 0; c < 2; ++c) {
            int k = wv * 2 + c;
            const unsigned short* gr = gtPb + (g * NS + w + 1 + k) * ND + lane * 4;
            ushort2 g01 = *(const ushort2*)gr;
            ushort2 g23 = *(const ushort2*)(gr + 2);
            const unsigned short* lp = &locS[k * 264 + lane * 4];
            float s = bf2f(lp[0]) * bf2f(g01.x) + bf2f(lp[1]) * bf2f(g01.y) +
                      bf2f(lp[2]) * bf2f(g23.x) + bf2f(lp[3]) * bf2f(g23.y);
            for (int off = 32; off; off >>= 1) s += __shfl_xor(s, off);
            if (!lane) spos[k] = s * (1.0f / 256.0f);
        }
    }

    // neg scores: 8 MFMAs, two independent accumulator chains
    const short8* aP = (const short8*)&locS[lm * 264 + quad * 8];
    f32x4 accA = {0.f, 0.f, 0.f, 0.f}, accB = {0.f, 0.f, 0.f, 0.f};
    accA = __builtin_amdgcn_mfma_f32_16x16x32_bf16(aP[0],  __builtin_bit_cast(short8, q0), accA, 0, 0, 0);
    accB = __builtin_amdgcn_mfma_f32_16x16x32_bf16(aP[4],  __builtin_bit_cast(short8, q1), accB, 0, 0, 0);
    accA = __builtin_amdgcn_mfma_f32_16x16x32_bf16(aP[8],  __builtin_bit_cast(short8, q2), accA, 0, 0, 0);
    accB = __builtin_amdgcn_mfma_f32_16x16x32_bf16(aP[12], __builtin_bit_cast(short8, q3), accB, 0, 0, 0);
    accA = __builtin_amdgcn_mfma_f32_16x16x32_bf16(aP[16], __builtin_bit_cast(short8, q4), accA, 0, 0, 0);
    accB = __builtin_amdgcn_mfma_f32_16x16x32_bf16(aP[20], __builtin_bit_cast(short8, q5), accB, 0, 0, 0);
    accA = __builtin_amdgcn_mfma_f32_16x16x32_bf16(aP[24], __builtin_bit_cast(short8, q6), accA, 0, 0, 0);
    accB = __builtin_amdgcn_mfma_f32_16x16x32_bf16(aP[28], __builtin_bit_cast(short8, q7), accB, 0, 0, 0);
    #pragma unroll
    for (int rr = 0; rr < 4; ++rr) {
        int k = quad * 4 + rr;
        if (k < NK) sc[k][n] = (accA[rr] + accB[rr]) * (1.0f / 256.0f);
    }
    __syncthreads();

    // per-k log-softmax over [pos, 128 negs]; 16-thread teams per k
    if (tid < NK * 16) {
        int k = tid >> 4, i = tid & 15;
        float vals[8];
        float mx = -1e30f;
        for (int j = 0; j < 8; ++j) {
            vals[j] = sc[k][i + 16 * j];
            mx = fmaxf(mx, vals[j]);
        }
        for (int off = 8; off > 0; off >>= 1) mx = fmaxf(mx, __shfl_xor(mx, off, 16));
        float negmax = mx;
        float sp = spos[k];
        float M = fmaxf(negmax, sp);
        float se = 0.f;
        for (int j = 0; j < 8; ++j) se += __expf(vals[j] - M);
        for (int off = 8; off > 0; off >>= 1) se += __shfl_xor(se, off, 16);
        if (i == 0) {
            float total = se + __expf(sp - M);
            float lp = sp - (M + __logf(total));
            partial[k * 1024 + bid]        = -lp;
            partial[(NK + k) * 1024 + bid] = (sp >= negmax) ? 1.0f : 0.0f;
        }
    }
}

// ---------- final reduce: 24 outputs, sum 1024 partials each ----------
__global__ __launch_bounds__(256) void k_reduce(const float* __restrict__ partial,
                                                float* __restrict__ out) {
    int j = blockIdx.x;                 // 0..23
    int tid = threadIdx.x;
    const float* p = partial + j * 1024;
    float s = p[tid] + p[tid + 256] + p[tid + 512] + p[tid + 768];
    for (int off = 32; off; off >>= 1) s += __shfl_xor(s, off);
    __shared__ float wsum[4];
    if ((tid & 63) == 0) wsum[tid >> 6] = s;
    __syncthreads();
    if (tid == 0) out[j] = (wsum[0] + wsum[1] + wsum[2] + wsum[3]) * (1.0f / 1024.0f);
}

extern "C" void kernel_launch(void* const* d_in, const int* in_sizes, int n_in,
                              void* d_out, int out_size, void* d_ws, size_t ws_size,
                              hipStream_t stream) {
    const float* cF     = (const float*)d_in[0];   // (8,140,256)
    const float* gtP    = (const float*)d_in[1];   // (8,140,256)
    const float* other  = (const float*)d_in[2];   // (20000,256)
    const int*   extIdx = (const int*)  d_in[3];   // (8,128,128)
    const float* Wm     = (const float*)d_in[4];   // (12,256,256)
    float* out = (float*)d_out;                    // 12 losses then 12 acc

    unsigned short* pool_bf = (unsigned short*)d_ws;       // 20000*256 shorts = 10.24 MB
    unsigned short* locC_bf = pool_bf + (long)POOLN * ND;  // 1024*3072 shorts = 6.29 MB
    unsigned short* gtP_bf  = locC_bf + (long)1024 * 3072; // 286720 shorts = 0.57 MB
    int* extIdxT = (int*)(gtP_bf + NG * NS * ND);          // 131072 ints = 512 KB
    float* partial = (float*)(extIdxT + 131072);           // 24*1024 floats = 96 KB

    k_prep<<<LOC_BLOCKS + CVT_BLOCKS + GTP_BLOCKS + TR_BLOCKS, 256, 0, stream>>>(
        cF, Wm, other, gtP, extIdx, pool_bf, gtP_bf, locC_bf, extIdxT);
    k_scores<<<1024, 512, 0, stream>>>(locC_bf, gtP_bf, pool_bf, extIdxT, partial);
    k_reduce<<<24, 256, 0, stream>>>(partial, out);
}